// Round 2
// baseline (267.712 us; speedup 1.0000x reference)
//
#include <hip/hip_runtime.h>
#include <hip/hip_bf16.h>

#define B_DIM   1024
#define N_DIM   2048
#define G_DIM   32
#define H1_DIM  2048
#define H2_DIM  512
#define BN_EPS  1e-5f
#define SLOPE   0.05f

typedef short v8s __attribute__((ext_vector_type(8)));
typedef float v4f __attribute__((ext_vector_type(4)));

__device__ __forceinline__ float lrelu_f(float v) { return v >= 0.f ? v : SLOPE * v; }

// async global->LDS, 16B per lane, linear LDS dest (wave-uniform base + lane*16)
#define GLOAD_LDS16(gp, lp)                                                              \
    __builtin_amdgcn_global_load_lds(                                                    \
        (const __attribute__((address_space(1))) unsigned int*)(gp),                     \
        (__attribute__((address_space(3))) unsigned int*)(lp), 16, 0, 0)

// ---------------------------------------------------------------- softmax(att_w)
__global__ __launch_bounds__(256) void softmax_kernel(const float* __restrict__ w,
                                                      float* __restrict__ att) {
    __shared__ float red[8];
    int t = threadIdx.x;
    float vals[8];
    float m = -1e30f;
#pragma unroll
    for (int i = 0; i < 8; ++i) { vals[i] = w[t + i * 256]; m = fmaxf(m, vals[i]); }
#pragma unroll
    for (int off = 32; off; off >>= 1) m = fmaxf(m, __shfl_down(m, off, 64));
    if ((t & 63) == 0) red[t >> 6] = m;
    __syncthreads();
    float M = fmaxf(fmaxf(red[0], red[1]), fmaxf(red[2], red[3]));
    float s = 0.f;
#pragma unroll
    for (int i = 0; i < 8; ++i) { vals[i] = expf(vals[i] - M); s += vals[i]; }
#pragma unroll
    for (int off = 32; off; off >>= 1) s += __shfl_down(s, off, 64);
    if ((t & 63) == 0) red[4 + (t >> 6)] = s;
    __syncthreads();
    float inv = 1.f / (red[4] + red[5] + red[6] + red[7]);
#pragma unroll
    for (int i = 0; i < 8; ++i) att[t + i * 256] = vals[i] * inv;
}

// ------------------------------------------- W [Kd][Jd] f32 -> Wt [Jd][Kd] bf16, optional row scale[k]
__global__ __launch_bounds__(256) void convert_transpose(const float* __restrict__ W,
                                                         const float* __restrict__ scale,
                                                         __hip_bfloat16* __restrict__ Wt,
                                                         int Kd, int Jd) {
    __shared__ float tile[64][65];
    int t = threadIdx.x;
    int j0 = blockIdx.x * 64, k0 = blockIdx.y * 64;
#pragma unroll
    for (int p = 0; p < 16; ++p) {
        int r = (t >> 6) + p * 4;
        int k = k0 + r;
        float v = W[(size_t)k * Jd + j0 + (t & 63)];
        if (scale) v *= scale[k];
        tile[r][t & 63] = v;
    }
    __syncthreads();
#pragma unroll
    for (int p = 0; p < 8; ++p) {
        int jr = (t >> 5) + p * 8;
        int kc = (t & 31) * 2;
        __hip_bfloat16 v0 = __float2bfloat16(tile[kc][jr]);
        __hip_bfloat16 v1 = __float2bfloat16(tile[kc + 1][jr]);
        ushort2 pk;
        pk.x = *(unsigned short*)&v0;
        pk.y = *(unsigned short*)&v1;
        *(ushort2*)(Wt + (size_t)(j0 + jr) * Kd + k0 + kc) = pk;
    }
}

// ------------------------------------------------ g[b][n] = lrelu(dot(x[b,n*32:], Wg[n]) + bg[n])
__global__ __launch_bounds__(256) void group_linear(const float* __restrict__ x,
                                                    const float* __restrict__ Wg,
                                                    const float* __restrict__ bg,
                                                    __hip_bfloat16* __restrict__ g) {
    int t = threadIdx.x;
    int n = blockIdx.x * 256 + t;
    float4 w[8];
    const float4* wsrc = (const float4*)(Wg + (size_t)n * 32);
#pragma unroll
    for (int i = 0; i < 8; ++i) w[i] = wsrc[i];
    float bgv = bg[n];
#pragma unroll
    for (int bb = 0; bb < 4; ++bb) {
        int b = blockIdx.y * 4 + bb;
        const float4* xr = (const float4*)(x + (size_t)b * (N_DIM * G_DIM) + (size_t)n * 32);
        float s = 0.f;
#pragma unroll
        for (int i = 0; i < 8; ++i) {
            float4 v = xr[i];
            s += v.x * w[i].x + v.y * w[i].y + v.z * w[i].z + v.w * w[i].w;
        }
        s = lrelu_f(s + bgv);
        g[(size_t)b * N_DIM + n] = __float2bfloat16(s);
    }
}

// ------------------------------------------------ C[M][N] f32 = A[M][K]bf16 @ Bt[N][K]bf16^T
// 64 x BN tile, BK=64, global_load_lds staging with XOR-swizzled layout
// (inverse-swizzled global SOURCE + swizzled ds_read; LDS dest stays linear).
// Fused epilogue: per-block column sum / sumsq -> ps/pq[blockIdx.x][N].
template<int BN>
__global__ __launch_bounds__((BN / 32) * 128) void gemm_stats(
        const __hip_bfloat16* __restrict__ A, const __hip_bfloat16* __restrict__ Bt,
        float* __restrict__ C, float* __restrict__ ps, float* __restrict__ pq,
        int N, int K) {
    constexpr int WN = BN / 32;     // wave cols
    constexpr int T  = WN * 128;    // threads (2 wave-rows x WN wave-cols)
    __shared__ __hip_bfloat16 A_s[64 * 64];
    __shared__ __hip_bfloat16 B_s[BN * 64];
    __shared__ float rs[2][BN], rq[2][BN];

    int tid = threadIdx.x, lane = tid & 63, wave = tid >> 6;
    int wr = wave / WN, wc = wave % WN;
    int rbase = blockIdx.x * 64, cbase = blockIdx.y * BN;
    int l15 = lane & 15, kq = lane >> 4;

    v4f acc[2][2] = {};

    const int nkt = K >> 6;
    for (int kt = 0; kt < nkt; ++kt) {
        int k0 = kt << 6;
        // stage A (64 rows x 64 k, 512 slots of 16B)
#pragma unroll
        for (int i = 0; i < 512 / T; ++i) {
            int s = tid + i * T;
            int row = s >> 3, cg = (s & 7) ^ (row & 7);
            GLOAD_LDS16(A + (size_t)(rbase + row) * K + k0 + cg * 8, (char*)A_s + s * 16);
        }
        // stage B (BN rows x 64 k)
#pragma unroll
        for (int i = 0; i < BN * 8 / T; ++i) {
            int s = tid + i * T;
            int row = s >> 3, cg = (s & 7) ^ (row & 7);
            GLOAD_LDS16(Bt + (size_t)(cbase + row) * K + k0 + cg * 8, (char*)B_s + s * 16);
        }
        __syncthreads();
#pragma unroll
        for (int kc = 0; kc < 2; ++kc) {
            v8s af[2], bfv[2];
#pragma unroll
            for (int m = 0; m < 2; ++m) {
                int row = wr * 32 + m * 16 + l15;
                int off = row * 128 + ((kc * 64 + kq * 16) ^ ((row & 7) << 4));
                af[m] = *(const v8s*)((const char*)A_s + off);
            }
#pragma unroll
            for (int n = 0; n < 2; ++n) {
                int row = wc * 32 + n * 16 + l15;
                int off = row * 128 + ((kc * 64 + kq * 16) ^ ((row & 7) << 4));
                bfv[n] = *(const v8s*)((const char*)B_s + off);
            }
#pragma unroll
            for (int m = 0; m < 2; ++m)
#pragma unroll
                for (int n = 0; n < 2; ++n)
                    acc[m][n] = __builtin_amdgcn_mfma_f32_16x16x32_bf16(af[m], bfv[n],
                                                                        acc[m][n], 0, 0, 0);
        }
        __syncthreads();
    }

    // ---- C write
    int crow = kq * 4;
#pragma unroll
    for (int m = 0; m < 2; ++m)
#pragma unroll
        for (int n = 0; n < 2; ++n) {
            int r = rbase + wr * 32 + m * 16 + crow;
            int c = cbase + wc * 32 + n * 16 + l15;
#pragma unroll
            for (int i = 0; i < 4; ++i)
                C[(size_t)(r + i) * N + c] = acc[m][n][i];
        }

    // ---- fused column stats (sum / sumsq over this block's 64 rows)
    float cs[2], cq[2];
#pragma unroll
    for (int n = 0; n < 2; ++n) {
        cs[n] = 0.f; cq[n] = 0.f;
#pragma unroll
        for (int m = 0; m < 2; ++m)
#pragma unroll
            for (int i = 0; i < 4; ++i) {
                float v = acc[m][n][i];
                cs[n] += v; cq[n] += v * v;
            }
#pragma unroll
        for (int off = 16; off <= 32; off <<= 1) {
            cs[n] += __shfl_xor(cs[n], off, 64);
            cq[n] += __shfl_xor(cq[n], off, 64);
        }
    }
    if (lane < 16) {
#pragma unroll
        for (int n = 0; n < 2; ++n) {
            rs[wr][wc * 32 + n * 16 + lane] = cs[n];
            rq[wr][wc * 32 + n * 16 + lane] = cq[n];
        }
    }
    __syncthreads();
    for (int c = tid; c < BN; c += T) {
        ps[(size_t)blockIdx.x * N + cbase + c] = rs[0][c] + rs[1][c];
        pq[(size_t)blockIdx.x * N + cbase + c] = rq[0][c] + rq[1][c];
    }
}

// ------------------------------------------------ finalize: scale = rstd*gamma, shift = beta - mu*scale
__global__ __launch_bounds__(256) void col_finalize(const float* __restrict__ ps,
                                                    const float* __restrict__ pq,
                                                    const float* __restrict__ gamma,
                                                    const float* __restrict__ beta,
                                                    float* __restrict__ scale,
                                                    float* __restrict__ shift,
                                                    int C, int nsplit, float invB) {
    int c = blockIdx.x * 256 + threadIdx.x;
    if (c >= C) return;
    float s = 0.f, q = 0.f;
    for (int i = 0; i < nsplit; ++i) {
        s += ps[(size_t)i * C + c];
        q += pq[(size_t)i * C + c];
    }
    float mu = s * invB;
    float var = q * invB - mu * mu;
    var = fmaxf(var, 0.f);
    float rsv = rsqrtf(var + BN_EPS);
    float sc = rsv * gamma[c];
    scale[c] = sc;
    shift[c] = beta[c] - mu * sc;
}

// ------------------------------------------------ h = bf16(lrelu(hraw*scale + shift))
__global__ __launch_bounds__(256) void bn_apply(const float* __restrict__ hraw,
                                                const float* __restrict__ scale,
                                                const float* __restrict__ shift,
                                                __hip_bfloat16* __restrict__ o, int Cmask) {
    size_t idx = ((size_t)blockIdx.x * 256 + threadIdx.x) * 4;
    int j = (int)(idx & (size_t)Cmask);
    float4 v = *(const float4*)(hraw + idx);
    float4 sc = *(const float4*)(scale + j);
    float4 sh = *(const float4*)(shift + j);
    float r0 = lrelu_f(v.x * sc.x + sh.x);
    float r1 = lrelu_f(v.y * sc.y + sh.y);
    float r2 = lrelu_f(v.z * sc.z + sh.z);
    float r3 = lrelu_f(v.w * sc.w + sh.w);
    __hip_bfloat16 o0 = __float2bfloat16(r0), o1 = __float2bfloat16(r1);
    __hip_bfloat16 o2 = __float2bfloat16(r2), o3 = __float2bfloat16(r3);
    ushort4 pk;
    pk.x = *(unsigned short*)&o0; pk.y = *(unsigned short*)&o1;
    pk.z = *(unsigned short*)&o2; pk.w = *(unsigned short*)&o3;
    *(ushort4*)(o + idx) = pk;
}

// ------------------------------------------------ out[b] = sum_j lrelu(bn(h2raw[b,j])) * Wo[j] + bo
__global__ __launch_bounds__(256) void bn_dot_out(const float* __restrict__ h2,
                                                  const float* __restrict__ scale2,
                                                  const float* __restrict__ shift2,
                                                  const float* __restrict__ Wo,
                                                  const float* __restrict__ bo,
                                                  float* __restrict__ out) {
    __shared__ float red[4];
    int b = blockIdx.x, t = threadIdx.x;
    float s = 0.f;
#pragma unroll
    for (int p = 0; p < 2; ++p) {
        int j = t + p * 256;
        float v = lrelu_f(h2[(size_t)b * H2_DIM + j] * scale2[j] + shift2[j]);
        s += v * Wo[j];
    }
#pragma unroll
    for (int off = 32; off; off >>= 1) s += __shfl_down(s, off, 64);
    if ((t & 63) == 0) red[t >> 6] = s;
    __syncthreads();
    if (t == 0) out[b] = red[0] + red[1] + red[2] + red[3] + bo[0];
}

// ================================================================ host
extern "C" void kernel_launch(void* const* d_in, const int* in_sizes, int n_in,
                              void* d_out, int out_size, void* d_ws, size_t ws_size,
                              hipStream_t stream) {
    const float* x     = (const float*)d_in[0];
    const float* Wg    = (const float*)d_in[1];
    const float* bg    = (const float*)d_in[2];
    const float* att_w = (const float*)d_in[3];
    const float* W1    = (const float*)d_in[4];
    const float* gamma1 = (const float*)d_in[6];
    const float* beta1  = (const float*)d_in[7];
    const float* W2    = (const float*)d_in[8];
    const float* gamma2 = (const float*)d_in[10];
    const float* beta2  = (const float*)d_in[11];
    const float* Wo    = (const float*)d_in[12];
    const float* bo    = (const float*)d_in[13];
    float* out = (float*)d_out;

    char* ws = (char*)d_ws;
    size_t off = 0;
    auto alloc = [&](size_t bytes) {
        void* p = ws + off;
        off = (off + bytes + 255) & ~(size_t)255;
        return p;
    };
    float*          att    = (float*)alloc(N_DIM * 4);
    __hip_bfloat16* W1T    = (__hip_bfloat16*)alloc((size_t)H1_DIM * N_DIM * 2);
    __hip_bfloat16* W2T    = (__hip_bfloat16*)alloc((size_t)H2_DIM * H1_DIM * 2);
    __hip_bfloat16* g      = (__hip_bfloat16*)alloc((size_t)B_DIM * N_DIM * 2);
    float*          h1raw  = (float*)alloc((size_t)B_DIM * H1_DIM * 4);
    __hip_bfloat16* h1     = (__hip_bfloat16*)alloc((size_t)B_DIM * H1_DIM * 2);
    float*          h2raw  = (float*)alloc((size_t)B_DIM * H2_DIM * 4);
    float*          ps     = (float*)alloc(32 * H1_DIM * 4);
    float*          pq     = (float*)alloc(32 * H1_DIM * 4);
    float*          scale1 = (float*)alloc(H1_DIM * 4);
    float*          shift1 = (float*)alloc(H1_DIM * 4);
    float*          scale2 = (float*)alloc(H2_DIM * 4);
    float*          shift2 = (float*)alloc(H2_DIM * 4);
    (void)ws_size; (void)in_sizes; (void)n_in; (void)out_size;

    // 1. softmax of attention weights
    softmax_kernel<<<1, 256, 0, stream>>>(att_w, att);
    // 2. W1T[j][k] = bf16(att[k] * W1[k][j]); W2T[j][k] = bf16(W2[k][j])
    convert_transpose<<<dim3(H1_DIM / 64, N_DIM / 64), 256, 0, stream>>>(W1, att, W1T, N_DIM, H1_DIM);
    convert_transpose<<<dim3(H2_DIM / 64, H1_DIM / 64), 256, 0, stream>>>(W2, nullptr, W2T, H1_DIM, H2_DIM);
    // 3. per-group linear + lrelu -> g bf16 [B, N]
    group_linear<<<dim3(N_DIM / 256, B_DIM / 4), 256, 0, stream>>>(x, Wg, bg, g);
    // 4. GEMM1 (+BN1 stats): h1raw = g @ (att*W1)
    gemm_stats<128><<<dim3(B_DIM / 64, H1_DIM / 128), 512, 0, stream>>>(g, W1T, h1raw, ps, pq,
                                                                        H1_DIM, N_DIM);
    // 5. finalize BN1
    col_finalize<<<dim3(H1_DIM / 256), 256, 0, stream>>>(ps, pq, gamma1, beta1, scale1, shift1,
                                                         H1_DIM, B_DIM / 64, 1.f / B_DIM);
    // 6. apply BN1 + lrelu -> h1 bf16
    bn_apply<<<dim3((B_DIM * H1_DIM) / (256 * 4)), 256, 0, stream>>>(h1raw, scale1, shift1, h1, H1_DIM - 1);
    // 7. GEMM2 (+BN2 stats): h2raw = h1 @ W2
    gemm_stats<64><<<dim3(B_DIM / 64, H2_DIM / 64), 256, 0, stream>>>(h1, W2T, h2raw, ps, pq,
                                                                      H2_DIM, H1_DIM);
    // 8. finalize BN2
    col_finalize<<<dim3((H2_DIM + 255) / 256), 256, 0, stream>>>(ps, pq, gamma2, beta2, scale2, shift2,
                                                                 H2_DIM, B_DIM / 64, 1.f / B_DIM);
    // 9. BN2 + lrelu + dot(Wo) + bo -> out [B]
    bn_dot_out<<<dim3(B_DIM), 256, 0, stream>>>(h2raw, scale2, shift2, Wo, bo, out);
}

// Round 3
// 150.712 us; speedup vs baseline: 1.7763x; 1.7763x over previous
//
#include <hip/hip_runtime.h>
#include <hip/hip_bf16.h>

#define B_DIM   1024
#define N_DIM   2048
#define G_DIM   32
#define H1_DIM  2048
#define H2_DIM  512
#define BN_EPS  1e-5f
#define SLOPE   0.05f

typedef short v8s __attribute__((ext_vector_type(8)));
typedef float v4f __attribute__((ext_vector_type(4)));

__device__ __forceinline__ float lrelu_f(float v) { return v >= 0.f ? v : SLOPE * v; }

// async global->LDS, 16B per lane, linear LDS dest (wave-uniform base + lane*16)
#define GLOAD_LDS16(gp, lp)                                                              \
    __builtin_amdgcn_global_load_lds(                                                    \
        (const __attribute__((address_space(1))) unsigned int*)(gp),                     \
        (__attribute__((address_space(3))) unsigned int*)(lp), 16, 0, 0)

// ---------------------------------------------------------------- softmax(att_w)
__global__ __launch_bounds__(256) void softmax_kernel(const float* __restrict__ w,
                                                      float* __restrict__ att) {
    __shared__ float red[8];
    int t = threadIdx.x;
    float vals[8];
    float m = -1e30f;
#pragma unroll
    for (int i = 0; i < 8; ++i) { vals[i] = w[t + i * 256]; m = fmaxf(m, vals[i]); }
#pragma unroll
    for (int off = 32; off; off >>= 1) m = fmaxf(m, __shfl_down(m, off, 64));
    if ((t & 63) == 0) red[t >> 6] = m;
    __syncthreads();
    float M = fmaxf(fmaxf(red[0], red[1]), fmaxf(red[2], red[3]));
    float s = 0.f;
#pragma unroll
    for (int i = 0; i < 8; ++i) { vals[i] = expf(vals[i] - M); s += vals[i]; }
#pragma unroll
    for (int off = 32; off; off >>= 1) s += __shfl_down(s, off, 64);
    if ((t & 63) == 0) red[4 + (t >> 6)] = s;
    __syncthreads();
    float inv = 1.f / (red[4] + red[5] + red[6] + red[7]);
#pragma unroll
    for (int i = 0; i < 8; ++i) att[t + i * 256] = vals[i] * inv;
}

// ------------------------------------------- W [Kd][Jd] f32 -> Wt [Jd][Kd] bf16, optional row scale[k]
__global__ __launch_bounds__(256) void convert_transpose(const float* __restrict__ W,
                                                         const float* __restrict__ scale,
                                                         __hip_bfloat16* __restrict__ Wt,
                                                         int Kd, int Jd) {
    __shared__ float tile[64][65];
    int t = threadIdx.x;
    int j0 = blockIdx.x * 64, k0 = blockIdx.y * 64;
#pragma unroll
    for (int p = 0; p < 16; ++p) {
        int r = (t >> 6) + p * 4;
        int k = k0 + r;
        float v = W[(size_t)k * Jd + j0 + (t & 63)];
        if (scale) v *= scale[k];
        tile[r][t & 63] = v;
    }
    __syncthreads();
#pragma unroll
    for (int p = 0; p < 8; ++p) {
        int jr = (t >> 5) + p * 8;
        int kc = (t & 31) * 2;
        __hip_bfloat16 v0 = __float2bfloat16(tile[kc][jr]);
        __hip_bfloat16 v1 = __float2bfloat16(tile[kc + 1][jr]);
        ushort2 pk;
        pk.x = *(unsigned short*)&v0;
        pk.y = *(unsigned short*)&v1;
        *(ushort2*)(Wt + (size_t)(j0 + jr) * Kd + k0 + kc) = pk;
    }
}

// ------------------------------------------------ g[b][n] = lrelu(dot(x[b,n*32:], Wg[n]) + bg[n])
// Fully-coalesced: block (brow, seg) processes 8 batch rows x 256 groups.
// Each thread owns float4 chunk (t&7) of group seg*256 + it*32 + (t>>3);
// 8-lane shfl_xor reduce. x loads are lane-contiguous 16B.
__global__ __launch_bounds__(256) void group_linear(const float* __restrict__ x,
                                                    const float* __restrict__ Wg,
                                                    const float* __restrict__ bg,
                                                    __hip_bfloat16* __restrict__ g) {
    int t = threadIdx.x;
    int seg = blockIdx.y;                 // 0..7, 256 groups each
    int brow = blockIdx.x;                // 0..127, 8 batch rows each
    int sub = t & 7;
    // preload this thread's Wg chunks + biases for its 8 (it) groups
    float4 wv[8];
    float bgv[8];
#pragma unroll
    for (int it = 0; it < 8; ++it) {
        int n = seg * 256 + it * 32 + (t >> 3);
        wv[it] = *(const float4*)(Wg + (size_t)n * 32 + sub * 4);
        bgv[it] = bg[n];
    }
#pragma unroll
    for (int bb = 0; bb < 8; ++bb) {
        int b = brow * 8 + bb;
        const float* xrow = x + (size_t)b * (N_DIM * G_DIM) + (size_t)seg * 8192;
#pragma unroll
        for (int it = 0; it < 8; ++it) {
            float4 xv = *(const float4*)(xrow + it * 1024 + t * 4);
            float s = xv.x * wv[it].x + xv.y * wv[it].y + xv.z * wv[it].z + xv.w * wv[it].w;
            s += __shfl_xor(s, 1, 64);
            s += __shfl_xor(s, 2, 64);
            s += __shfl_xor(s, 4, 64);
            if (sub == 0) {
                int n = seg * 256 + it * 32 + (t >> 3);
                g[(size_t)b * N_DIM + n] = __float2bfloat16(lrelu_f(s + bgv[it]));
            }
        }
    }
}

// ------------------------------------------------ C[M][N] f32 = A[M][K]bf16 @ Bt[N][K]bf16^T
// 64 x BN tile, BK=64, double-buffered global_load_lds staging (2-phase: issue
// next tile's loads BEFORE computing current; one barrier per step).
// XOR-swizzled layout: inverse-swizzled global SOURCE + swizzled ds_read.
// Fused epilogue: per-block column sum / sumsq -> ps/pq[blockIdx.x][N].
template<int BN>
__global__ __launch_bounds__((BN / 32) * 128) void gemm_stats(
        const __hip_bfloat16* __restrict__ A, const __hip_bfloat16* __restrict__ Bt,
        float* __restrict__ C, float* __restrict__ ps, float* __restrict__ pq,
        int N, int K) {
    constexpr int WN = BN / 32;     // wave cols
    constexpr int T  = WN * 128;    // threads (2 wave-rows x WN wave-cols)
    __shared__ __hip_bfloat16 A_s[2][64 * 64];
    __shared__ __hip_bfloat16 B_s[2][BN * 64];
    __shared__ float rs[2][BN], rq[2][BN];

    int tid = threadIdx.x, lane = tid & 63, wave = tid >> 6;
    int wr = wave / WN, wc = wave % WN;
    int rbase = blockIdx.x * 64, cbase = blockIdx.y * BN;
    int l15 = lane & 15, kq = lane >> 4;

    v4f acc[2][2] = {};

    auto stage = [&](int buf, int kt) {
        int k0 = kt << 6;
#pragma unroll
        for (int i = 0; i < 512 / T; ++i) {
            int s = tid + i * T;
            int row = s >> 3, cg = (s & 7) ^ (row & 7);
            GLOAD_LDS16(A + (size_t)(rbase + row) * K + k0 + cg * 8, (char*)A_s[buf] + s * 16);
        }
#pragma unroll
        for (int i = 0; i < BN * 8 / T; ++i) {
            int s = tid + i * T;
            int row = s >> 3, cg = (s & 7) ^ (row & 7);
            GLOAD_LDS16(Bt + (size_t)(cbase + row) * K + k0 + cg * 8, (char*)B_s[buf] + s * 16);
        }
    };

    const int nkt = K >> 6;
    stage(0, 0);
    __syncthreads();          // drain prologue loads
    int cur = 0;
    for (int kt = 0; kt < nkt; ++kt) {
        if (kt + 1 < nkt) stage(cur ^ 1, kt + 1);   // prefetch next tile (async)
#pragma unroll
        for (int kc = 0; kc < 2; ++kc) {
            v8s af[2], bfv[2];
#pragma unroll
            for (int m = 0; m < 2; ++m) {
                int row = wr * 32 + m * 16 + l15;
                int off = row * 128 + ((kc * 64 + kq * 16) ^ ((row & 7) << 4));
                af[m] = *(const v8s*)((const char*)A_s[cur] + off);
            }
#pragma unroll
            for (int n = 0; n < 2; ++n) {
                int row = wc * 32 + n * 16 + l15;
                int off = row * 128 + ((kc * 64 + kq * 16) ^ ((row & 7) << 4));
                bfv[n] = *(const v8s*)((const char*)B_s[cur] + off);
            }
#pragma unroll
            for (int m = 0; m < 2; ++m)
#pragma unroll
                for (int n = 0; n < 2; ++n)
                    acc[m][n] = __builtin_amdgcn_mfma_f32_16x16x32_bf16(af[m], bfv[n],
                                                                        acc[m][n], 0, 0, 0);
        }
        __syncthreads();      // drains prefetch vmcnt + guards buffer reuse
        cur ^= 1;
    }

    // ---- C write
    int crow = kq * 4;
#pragma unroll
    for (int m = 0; m < 2; ++m)
#pragma unroll
        for (int n = 0; n < 2; ++n) {
            int r = rbase + wr * 32 + m * 16 + crow;
            int c = cbase + wc * 32 + n * 16 + l15;
#pragma unroll
            for (int i = 0; i < 4; ++i)
                C[(size_t)(r + i) * N + c] = acc[m][n][i];
        }

    // ---- fused column stats (sum / sumsq over this block's 64 rows)
    float cs[2], cq[2];
#pragma unroll
    for (int n = 0; n < 2; ++n) {
        cs[n] = 0.f; cq[n] = 0.f;
#pragma unroll
        for (int m = 0; m < 2; ++m)
#pragma unroll
            for (int i = 0; i < 4; ++i) {
                float v = acc[m][n][i];
                cs[n] += v; cq[n] += v * v;
            }
#pragma unroll
        for (int off = 16; off <= 32; off <<= 1) {
            cs[n] += __shfl_xor(cs[n], off, 64);
            cq[n] += __shfl_xor(cq[n], off, 64);
        }
    }
    if (lane < 16) {
#pragma unroll
        for (int n = 0; n < 2; ++n) {
            rs[wr][wc * 32 + n * 16 + lane] = cs[n];
            rq[wr][wc * 32 + n * 16 + lane] = cq[n];
        }
    }
    __syncthreads();
    for (int c = tid; c < BN; c += T) {
        ps[(size_t)blockIdx.x * N + cbase + c] = rs[0][c] + rs[1][c];
        pq[(size_t)blockIdx.x * N + cbase + c] = rq[0][c] + rq[1][c];
    }
}

// ------------------------------------------------ finalize: scale = rstd*gamma, shift = beta - mu*scale
__global__ __launch_bounds__(256) void col_finalize(const float* __restrict__ ps,
                                                    const float* __restrict__ pq,
                                                    const float* __restrict__ gamma,
                                                    const float* __restrict__ beta,
                                                    float* __restrict__ scale,
                                                    float* __restrict__ shift,
                                                    int C, int nsplit, float invB) {
    int c = blockIdx.x * 256 + threadIdx.x;
    if (c >= C) return;
    float s = 0.f, q = 0.f;
    for (int i = 0; i < nsplit; ++i) {
        s += ps[(size_t)i * C + c];
        q += pq[(size_t)i * C + c];
    }
    float mu = s * invB;
    float var = q * invB - mu * mu;
    var = fmaxf(var, 0.f);
    float rsv = rsqrtf(var + BN_EPS);
    float sc = rsv * gamma[c];
    scale[c] = sc;
    shift[c] = beta[c] - mu * sc;
}

// ------------------------------------------------ h = bf16(lrelu(hraw*scale + shift))
__global__ __launch_bounds__(256) void bn_apply(const float* __restrict__ hraw,
                                                const float* __restrict__ scale,
                                                const float* __restrict__ shift,
                                                __hip_bfloat16* __restrict__ o, int Cmask) {
    size_t idx = ((size_t)blockIdx.x * 256 + threadIdx.x) * 4;
    int j = (int)(idx & (size_t)Cmask);
    float4 v = *(const float4*)(hraw + idx);
    float4 sc = *(const float4*)(scale + j);
    float4 sh = *(const float4*)(shift + j);
    float r0 = lrelu_f(v.x * sc.x + sh.x);
    float r1 = lrelu_f(v.y * sc.y + sh.y);
    float r2 = lrelu_f(v.z * sc.z + sh.z);
    float r3 = lrelu_f(v.w * sc.w + sh.w);
    __hip_bfloat16 o0 = __float2bfloat16(r0), o1 = __float2bfloat16(r1);
    __hip_bfloat16 o2 = __float2bfloat16(r2), o3 = __float2bfloat16(r3);
    ushort4 pk;
    pk.x = *(unsigned short*)&o0; pk.y = *(unsigned short*)&o1;
    pk.z = *(unsigned short*)&o2; pk.w = *(unsigned short*)&o3;
    *(ushort4*)(o + idx) = pk;
}

// ------------------------------------------------ out[b] = sum_j lrelu(bn(h2raw[b,j])) * Wo[j] + bo
__global__ __launch_bounds__(256) void bn_dot_out(const float* __restrict__ h2,
                                                  const float* __restrict__ scale2,
                                                  const float* __restrict__ shift2,
                                                  const float* __restrict__ Wo,
                                                  const float* __restrict__ bo,
                                                  float* __restrict__ out) {
    __shared__ float red[4];
    int b = blockIdx.x, t = threadIdx.x;
    float s = 0.f;
#pragma unroll
    for (int p = 0; p < 2; ++p) {
        int j = t + p * 256;
        float v = lrelu_f(h2[(size_t)b * H2_DIM + j] * scale2[j] + shift2[j]);
        s += v * Wo[j];
    }
#pragma unroll
    for (int off = 32; off; off >>= 1) s += __shfl_down(s, off, 64);
    if ((t & 63) == 0) red[t >> 6] = s;
    __syncthreads();
    if (t == 0) out[b] = red[0] + red[1] + red[2] + red[3] + bo[0];
}

// ================================================================ host
extern "C" void kernel_launch(void* const* d_in, const int* in_sizes, int n_in,
                              void* d_out, int out_size, void* d_ws, size_t ws_size,
                              hipStream_t stream) {
    const float* x     = (const float*)d_in[0];
    const float* Wg    = (const float*)d_in[1];
    const float* bg    = (const float*)d_in[2];
    const float* att_w = (const float*)d_in[3];
    const float* W1    = (const float*)d_in[4];
    const float* gamma1 = (const float*)d_in[6];
    const float* beta1  = (const float*)d_in[7];
    const float* W2    = (const float*)d_in[8];
    const float* gamma2 = (const float*)d_in[10];
    const float* beta2  = (const float*)d_in[11];
    const float* Wo    = (const float*)d_in[12];
    const float* bo    = (const float*)d_in[13];
    float* out = (float*)d_out;

    char* ws = (char*)d_ws;
    size_t off = 0;
    auto alloc = [&](size_t bytes) {
        void* p = ws + off;
        off = (off + bytes + 255) & ~(size_t)255;
        return p;
    };
    float*          att    = (float*)alloc(N_DIM * 4);
    __hip_bfloat16* W1T    = (__hip_bfloat16*)alloc((size_t)H1_DIM * N_DIM * 2);
    __hip_bfloat16* W2T    = (__hip_bfloat16*)alloc((size_t)H2_DIM * H1_DIM * 2);
    __hip_bfloat16* g      = (__hip_bfloat16*)alloc((size_t)B_DIM * N_DIM * 2);
    float*          h1raw  = (float*)alloc((size_t)B_DIM * H1_DIM * 4);
    __hip_bfloat16* h1     = (__hip_bfloat16*)alloc((size_t)B_DIM * H1_DIM * 2);
    float*          h2raw  = (float*)alloc((size_t)B_DIM * H2_DIM * 4);
    float*          ps     = (float*)alloc(32 * H1_DIM * 4);
    float*          pq     = (float*)alloc(32 * H1_DIM * 4);
    float*          scale1 = (float*)alloc(H1_DIM * 4);
    float*          shift1 = (float*)alloc(H1_DIM * 4);
    float*          scale2 = (float*)alloc(H2_DIM * 4);
    float*          shift2 = (float*)alloc(H2_DIM * 4);
    (void)ws_size; (void)in_sizes; (void)n_in; (void)out_size;

    // 1. softmax of attention weights
    softmax_kernel<<<1, 256, 0, stream>>>(att_w, att);
    // 2. W1T[j][k] = bf16(att[k] * W1[k][j]); W2T[j][k] = bf16(W2[k][j])
    convert_transpose<<<dim3(H1_DIM / 64, N_DIM / 64), 256, 0, stream>>>(W1, att, W1T, N_DIM, H1_DIM);
    convert_transpose<<<dim3(H2_DIM / 64, H1_DIM / 64), 256, 0, stream>>>(W2, nullptr, W2T, H1_DIM, H2_DIM);
    // 3. per-group linear + lrelu -> g bf16 [B, N]  (coalesced shuffle-reduce version)
    group_linear<<<dim3(B_DIM / 8, 8), 256, 0, stream>>>(x, Wg, bg, g);
    // 4. GEMM1 (+BN1 stats): h1raw = g @ (att*W1)
    gemm_stats<128><<<dim3(B_DIM / 64, H1_DIM / 128), 512, 0, stream>>>(g, W1T, h1raw, ps, pq,
                                                                        H1_DIM, N_DIM);
    // 5. finalize BN1
    col_finalize<<<dim3(H1_DIM / 256), 256, 0, stream>>>(ps, pq, gamma1, beta1, scale1, shift1,
                                                         H1_DIM, B_DIM / 64, 1.f / B_DIM);
    // 6. apply BN1 + lrelu -> h1 bf16
    bn_apply<<<dim3((B_DIM * H1_DIM) / (256 * 4)), 256, 0, stream>>>(h1raw, scale1, shift1, h1, H1_DIM - 1);
    // 7. GEMM2 (+BN2 stats): h2raw = h1 @ W2
    gemm_stats<64><<<dim3(B_DIM / 64, H2_DIM / 64), 256, 0, stream>>>(h1, W2T, h2raw, ps, pq,
                                                                      H2_DIM, H1_DIM);
    // 8. finalize BN2
    col_finalize<<<dim3((H2_DIM + 255) / 256), 256, 0, stream>>>(ps, pq, gamma2, beta2, scale2, shift2,
                                                                 H2_DIM, B_DIM / 64, 1.f / B_DIM);
    // 9. BN2 + lrelu + dot(Wo) + bo -> out [B]
    bn_dot_out<<<dim3(B_DIM), 256, 0, stream>>>(h2raw, scale2, shift2, Wo, bo, out);
}

// Round 4
// 134.403 us; speedup vs baseline: 1.9919x; 1.1213x over previous
//
#include <hip/hip_runtime.h>
#include <hip/hip_bf16.h>

#define B_DIM   1024
#define N_DIM   2048
#define G_DIM   32
#define H1_DIM  2048
#define H2_DIM  512
#define BN_EPS  1e-5f
#define SLOPE   0.05f

typedef short v8s __attribute__((ext_vector_type(8)));
typedef float v4f __attribute__((ext_vector_type(4)));

__device__ __forceinline__ float lrelu_f(float v) { return v >= 0.f ? v : SLOPE * v; }
__device__ __forceinline__ float bf2f(unsigned short u) {
    unsigned int v = ((unsigned int)u) << 16;
    union { unsigned int i; float f; } c; c.i = v; return c.f;
}
__device__ __forceinline__ unsigned short f2bf(float f) {
    __hip_bfloat16 h = __float2bfloat16(f);
    return *(unsigned short*)&h;
}

// async global->LDS, 16B per lane, linear LDS dest (wave-uniform base + lane*16)
#define GLOAD_LDS16(gp, lp)                                                              \
    __builtin_amdgcn_global_load_lds(                                                    \
        (const __attribute__((address_space(1))) unsigned int*)(gp),                     \
        (__attribute__((address_space(3))) unsigned int*)(lp), 16, 0, 0)

// ---------------------------------------------------------------- softmax(att_w)
__global__ __launch_bounds__(256) void softmax_kernel(const float* __restrict__ w,
                                                      float* __restrict__ att) {
    __shared__ float red[8];
    int t = threadIdx.x;
    float vals[8];
    float m = -1e30f;
#pragma unroll
    for (int i = 0; i < 8; ++i) { vals[i] = w[t + i * 256]; m = fmaxf(m, vals[i]); }
#pragma unroll
    for (int off = 32; off; off >>= 1) m = fmaxf(m, __shfl_down(m, off, 64));
    if ((t & 63) == 0) red[t >> 6] = m;
    __syncthreads();
    float M = fmaxf(fmaxf(red[0], red[1]), fmaxf(red[2], red[3]));
    float s = 0.f;
#pragma unroll
    for (int i = 0; i < 8; ++i) { vals[i] = expf(vals[i] - M); s += vals[i]; }
#pragma unroll
    for (int off = 32; off; off >>= 1) s += __shfl_down(s, off, 64);
    if ((t & 63) == 0) red[4 + (t >> 6)] = s;
    __syncthreads();
    float inv = 1.f / (red[4] + red[5] + red[6] + red[7]);
#pragma unroll
    for (int i = 0; i < 8; ++i) att[t + i * 256] = vals[i] * inv;
}

// ------------------------------------------- W [Kd][Jd] f32 -> Wt [Jd][Kd] bf16, optional row scale[k]
__global__ __launch_bounds__(256) void convert_transpose(const float* __restrict__ W,
                                                         const float* __restrict__ scale,
                                                         __hip_bfloat16* __restrict__ Wt,
                                                         int Kd, int Jd) {
    __shared__ float tile[64][65];
    int t = threadIdx.x;
    int j0 = blockIdx.x * 64, k0 = blockIdx.y * 64;
#pragma unroll
    for (int p = 0; p < 16; ++p) {
        int r = (t >> 6) + p * 4;
        int k = k0 + r;
        float v = W[(size_t)k * Jd + j0 + (t & 63)];
        if (scale) v *= scale[k];
        tile[r][t & 63] = v;
    }
    __syncthreads();
#pragma unroll
    for (int p = 0; p < 8; ++p) {
        int jr = (t >> 5) + p * 8;
        int kc = (t & 31) * 2;
        ushort2 pk;
        pk.x = f2bf(tile[kc][jr]);
        pk.y = f2bf(tile[kc + 1][jr]);
        *(ushort2*)(Wt + (size_t)(j0 + jr) * Kd + k0 + kc) = pk;
    }
}

// ------------------------------------------------ g[b][n] = lrelu(dot(x[b,n*32:], Wg[n]) + bg[n])
// 2 lanes per group (16 elems each): fully-coalesced 64B/lane x reads, 1 shfl.
__global__ __launch_bounds__(256) void group_linear(const float* __restrict__ x,
                                                    const float* __restrict__ Wg,
                                                    const float* __restrict__ bg,
                                                    __hip_bfloat16* __restrict__ g) {
    int t = threadIdx.x;
    int seg = blockIdx.y;                 // 16 segs x 128 groups
    int brow = blockIdx.x;                // 128 brows x 8 batch rows
    int gl = t >> 1, half = t & 1;
    int n = seg * 128 + gl;
    float4 wv[4];
    const float4* wsrc = (const float4*)(Wg + (size_t)n * 32 + half * 16);
#pragma unroll
    for (int q = 0; q < 4; ++q) wv[q] = wsrc[q];
    float bgv = bg[n];
#pragma unroll
    for (int bb = 0; bb < 8; ++bb) {
        int b = brow * 8 + bb;
        const float4* xr = (const float4*)(x + (size_t)b * (N_DIM * G_DIM) + (size_t)n * 32 + half * 16);
        float s = 0.f;
#pragma unroll
        for (int q = 0; q < 4; ++q) {
            float4 v = xr[q];
            s += v.x * wv[q].x + v.y * wv[q].y + v.z * wv[q].z + v.w * wv[q].w;
        }
        s += __shfl_xor(s, 1, 64);
        if (half == 0)
            g[(size_t)b * N_DIM + n] = __float2bfloat16(lrelu_f(s + bgv));
    }
}

// ------------------------------------------------ C[M][N] = A[M][K]bf16 @ Bt[N][K]bf16^T
// 64x64 tile, 4 waves (2x2, each 32x32), BK=64, double-buffered global_load_lds
// (2-phase: issue next tile BEFORE computing current). XOR-swizzled LDS layout.
// Grid 512 (GEMM1) -> 2 blocks/CU for cross-block overlap. XCD-chunk swizzle.
// Fused epilogue: per-block column sum / sumsq -> ps/pq[block_row][N].
template<typename OutT>
__global__ __launch_bounds__(256) void gemm_stats(
        const __hip_bfloat16* __restrict__ A, const __hip_bfloat16* __restrict__ Bt,
        OutT* __restrict__ C, float* __restrict__ ps, float* __restrict__ pq,
        int N, int K) {
    __shared__ __hip_bfloat16 A_s[2][64 * 64];
    __shared__ __hip_bfloat16 B_s[2][64 * 64];
    __shared__ float rs[2][64], rq[2][64];

    // XCD-aware bijective block swizzle (grid size is a multiple of 8)
    int nwg = gridDim.x * gridDim.y;
    int bid = blockIdx.y * gridDim.x + blockIdx.x;
    int cpx = nwg >> 3;
    int wg  = (bid & 7) * cpx + (bid >> 3);
    int bx  = wg % gridDim.x, by = wg / gridDim.x;

    int tid = threadIdx.x, lane = tid & 63, wave = tid >> 6;
    int wr = wave >> 1, wc = wave & 1;
    int rbase = bx * 64, cbase = by * 64;
    int l15 = lane & 15, kq = lane >> 4;

    v4f acc[2][2] = {};

    auto stage = [&](int buf, int kt) {
        int k0 = kt << 6;
#pragma unroll
        for (int i = 0; i < 2; ++i) {
            int s = tid + i * 256;
            int row = s >> 3, cg = (s & 7) ^ (row & 7);
            GLOAD_LDS16(A + (size_t)(rbase + row) * K + k0 + cg * 8, (char*)A_s[buf] + s * 16);
        }
#pragma unroll
        for (int i = 0; i < 2; ++i) {
            int s = tid + i * 256;
            int row = s >> 3, cg = (s & 7) ^ (row & 7);
            GLOAD_LDS16(Bt + (size_t)(cbase + row) * K + k0 + cg * 8, (char*)B_s[buf] + s * 16);
        }
    };

    const int nkt = K >> 6;
    stage(0, 0);
    __syncthreads();
    int cur = 0;
    for (int kt = 0; kt < nkt; ++kt) {
        if (kt + 1 < nkt) stage(cur ^ 1, kt + 1);
#pragma unroll
        for (int kc = 0; kc < 2; ++kc) {
            v8s af[2], bfv[2];
#pragma unroll
            for (int m = 0; m < 2; ++m) {
                int row = wr * 32 + m * 16 + l15;
                int off = row * 128 + ((kc * 64 + kq * 16) ^ ((row & 7) << 4));
                af[m] = *(const v8s*)((const char*)A_s[cur] + off);
            }
#pragma unroll
            for (int n = 0; n < 2; ++n) {
                int row = wc * 32 + n * 16 + l15;
                int off = row * 128 + ((kc * 64 + kq * 16) ^ ((row & 7) << 4));
                bfv[n] = *(const v8s*)((const char*)B_s[cur] + off);
            }
#pragma unroll
            for (int m = 0; m < 2; ++m)
#pragma unroll
                for (int n = 0; n < 2; ++n)
                    acc[m][n] = __builtin_amdgcn_mfma_f32_16x16x32_bf16(af[m], bfv[n],
                                                                        acc[m][n], 0, 0, 0);
        }
        __syncthreads();
        cur ^= 1;
    }

    // ---- C write
    int crow = kq * 4;
#pragma unroll
    for (int m = 0; m < 2; ++m)
#pragma unroll
        for (int n = 0; n < 2; ++n) {
            int r = rbase + wr * 32 + m * 16 + crow;
            int c = cbase + wc * 32 + n * 16 + l15;
#pragma unroll
            for (int i = 0; i < 4; ++i) {
                float v = acc[m][n][i];
                if constexpr (sizeof(OutT) == 2)
                    ((__hip_bfloat16*)C)[(size_t)(r + i) * N + c] = __float2bfloat16(v);
                else
                    ((float*)C)[(size_t)(r + i) * N + c] = v;
            }
        }

    // ---- fused column stats (sum / sumsq over this block's 64 rows)
    float cs[2], cq[2];
#pragma unroll
    for (int n = 0; n < 2; ++n) {
        cs[n] = 0.f; cq[n] = 0.f;
#pragma unroll
        for (int m = 0; m < 2; ++m)
#pragma unroll
            for (int i = 0; i < 4; ++i) {
                float v = acc[m][n][i];
                cs[n] += v; cq[n] += v * v;
            }
#pragma unroll
        for (int off = 16; off <= 32; off <<= 1) {
            cs[n] += __shfl_xor(cs[n], off, 64);
            cq[n] += __shfl_xor(cq[n], off, 64);
        }
    }
    if (lane < 16) {
#pragma unroll
        for (int n = 0; n < 2; ++n) {
            rs[wr][wc * 32 + n * 16 + lane] = cs[n];
            rq[wr][wc * 32 + n * 16 + lane] = cq[n];
        }
    }
    __syncthreads();
    if (tid < 64) {
        // atomic-free: one partial row per block-row index bx
        ps[(size_t)bx * N + cbase + tid] += 0.f;  // keep compiler from reordering (no-op)
        ps[(size_t)bx * N + cbase + tid] = rs[0][tid] + rs[1][tid];
        pq[(size_t)bx * N + cbase + tid] = rq[0][tid] + rq[1][tid];
    }
}

// ------------------------------------------------ finalize: scale = rstd*gamma, shift = beta - mu*scale
__global__ __launch_bounds__(256) void col_finalize(const float* __restrict__ ps,
                                                    const float* __restrict__ pq,
                                                    const float* __restrict__ gamma,
                                                    const float* __restrict__ beta,
                                                    float* __restrict__ scale,
                                                    float* __restrict__ shift,
                                                    int C, int nsplit, float invB) {
    int c = blockIdx.x * 256 + threadIdx.x;
    if (c >= C) return;
    float s = 0.f, q = 0.f;
    for (int i = 0; i < nsplit; ++i) {
        s += ps[(size_t)i * C + c];
        q += pq[(size_t)i * C + c];
    }
    float mu = s * invB;
    float var = q * invB - mu * mu;
    var = fmaxf(var, 0.f);
    float rsv = rsqrtf(var + BN_EPS);
    float sc = rsv * gamma[c];
    scale[c] = sc;
    shift[c] = beta[c] - mu * sc;
}

// ------------------------------------------------ h1 = bf16(lrelu(h1pre*scale + shift)), bf16 in/out
__global__ __launch_bounds__(256) void bn_apply(const __hip_bfloat16* __restrict__ hpre,
                                                const float* __restrict__ scale,
                                                const float* __restrict__ shift,
                                                __hip_bfloat16* __restrict__ o, int Cmask) {
    size_t idx = ((size_t)blockIdx.x * 256 + threadIdx.x) * 8;
    int j = (int)(idx & (size_t)Cmask);
    v8s v = *(const v8s*)(hpre + idx);
    float4 sc0 = *(const float4*)(scale + j);
    float4 sc1 = *(const float4*)(scale + j + 4);
    float4 sh0 = *(const float4*)(shift + j);
    float4 sh1 = *(const float4*)(shift + j + 4);
    unsigned short r[8];
    r[0] = f2bf(lrelu_f(bf2f((unsigned short)v[0]) * sc0.x + sh0.x));
    r[1] = f2bf(lrelu_f(bf2f((unsigned short)v[1]) * sc0.y + sh0.y));
    r[2] = f2bf(lrelu_f(bf2f((unsigned short)v[2]) * sc0.z + sh0.z));
    r[3] = f2bf(lrelu_f(bf2f((unsigned short)v[3]) * sc0.w + sh0.w));
    r[4] = f2bf(lrelu_f(bf2f((unsigned short)v[4]) * sc1.x + sh1.x));
    r[5] = f2bf(lrelu_f(bf2f((unsigned short)v[5]) * sc1.y + sh1.y));
    r[6] = f2bf(lrelu_f(bf2f((unsigned short)v[6]) * sc1.z + sh1.z));
    r[7] = f2bf(lrelu_f(bf2f((unsigned short)v[7]) * sc1.w + sh1.w));
    v8s pk;
#pragma unroll
    for (int i = 0; i < 8; ++i) pk[i] = (short)r[i];
    *(v8s*)(o + idx) = pk;
}

// ------------------------------------------------ out[b] = sum_j lrelu(bn(h2raw[b,j])) * Wo[j] + bo
__global__ __launch_bounds__(256) void bn_dot_out(const float* __restrict__ h2,
                                                  const float* __restrict__ scale2,
                                                  const float* __restrict__ shift2,
                                                  const float* __restrict__ Wo,
                                                  const float* __restrict__ bo,
                                                  float* __restrict__ out) {
    __shared__ float red[4];
    int b = blockIdx.x, t = threadIdx.x;
    float s = 0.f;
#pragma unroll
    for (int p = 0; p < 2; ++p) {
        int j = t + p * 256;
        float v = lrelu_f(h2[(size_t)b * H2_DIM + j] * scale2[j] + shift2[j]);
        s += v * Wo[j];
    }
#pragma unroll
    for (int off = 32; off; off >>= 1) s += __shfl_down(s, off, 64);
    if ((t & 63) == 0) red[t >> 6] = s;
    __syncthreads();
    if (t == 0) out[b] = red[0] + red[1] + red[2] + red[3] + bo[0];
}

// ================================================================ host
extern "C" void kernel_launch(void* const* d_in, const int* in_sizes, int n_in,
                              void* d_out, int out_size, void* d_ws, size_t ws_size,
                              hipStream_t stream) {
    const float* x     = (const float*)d_in[0];
    const float* Wg    = (const float*)d_in[1];
    const float* bg    = (const float*)d_in[2];
    const float* att_w = (const float*)d_in[3];
    const float* W1    = (const float*)d_in[4];
    const float* gamma1 = (const float*)d_in[6];
    const float* beta1  = (const float*)d_in[7];
    const float* W2    = (const float*)d_in[8];
    const float* gamma2 = (const float*)d_in[10];
    const float* beta2  = (const float*)d_in[11];
    const float* Wo    = (const float*)d_in[12];
    const float* bo    = (const float*)d_in[13];
    float* out = (float*)d_out;

    char* ws = (char*)d_ws;
    size_t off = 0;
    auto alloc = [&](size_t bytes) {
        void* p = ws + off;
        off = (off + bytes + 255) & ~(size_t)255;
        return p;
    };
    float*          att    = (float*)alloc(N_DIM * 4);
    __hip_bfloat16* W1T    = (__hip_bfloat16*)alloc((size_t)H1_DIM * N_DIM * 2);
    __hip_bfloat16* W2T    = (__hip_bfloat16*)alloc((size_t)H2_DIM * H1_DIM * 2);
    __hip_bfloat16* g      = (__hip_bfloat16*)alloc((size_t)B_DIM * N_DIM * 2);
    __hip_bfloat16* h1pre  = (__hip_bfloat16*)alloc((size_t)B_DIM * H1_DIM * 2);
    __hip_bfloat16* h1     = (__hip_bfloat16*)alloc((size_t)B_DIM * H1_DIM * 2);
    float*          h2raw  = (float*)alloc((size_t)B_DIM * H2_DIM * 4);
    float*          ps     = (float*)alloc(32 * H1_DIM * 4);
    float*          pq     = (float*)alloc(32 * H1_DIM * 4);
    float*          scale1 = (float*)alloc(H1_DIM * 4);
    float*          shift1 = (float*)alloc(H1_DIM * 4);
    float*          scale2 = (float*)alloc(H2_DIM * 4);
    float*          shift2 = (float*)alloc(H2_DIM * 4);
    (void)ws_size; (void)in_sizes; (void)n_in; (void)out_size;

    // 1. softmax of attention weights
    softmax_kernel<<<1, 256, 0, stream>>>(att_w, att);
    // 2. W1T[j][k] = bf16(att[k] * W1[k][j]); W2T[j][k] = bf16(W2[k][j])
    convert_transpose<<<dim3(H1_DIM / 64, N_DIM / 64), 256, 0, stream>>>(W1, att, W1T, N_DIM, H1_DIM);
    convert_transpose<<<dim3(H2_DIM / 64, H1_DIM / 64), 256, 0, stream>>>(W2, nullptr, W2T, H1_DIM, H2_DIM);
    // 3. per-group linear + lrelu -> g bf16 [B, N]
    group_linear<<<dim3(B_DIM / 8, N_DIM / 128), 256, 0, stream>>>(x, Wg, bg, g);
    // 4. GEMM1 (+BN1 stats): h1pre = bf16(g @ (att*W1))
    gemm_stats<__hip_bfloat16><<<dim3(B_DIM / 64, H1_DIM / 64), 256, 0, stream>>>(
        g, W1T, h1pre, ps, pq, H1_DIM, N_DIM);
    // 5. finalize BN1
    col_finalize<<<dim3(H1_DIM / 256), 256, 0, stream>>>(ps, pq, gamma1, beta1, scale1, shift1,
                                                         H1_DIM, B_DIM / 64, 1.f / B_DIM);
    // 6. apply BN1 + lrelu -> h1 bf16
    bn_apply<<<dim3((B_DIM * H1_DIM) / (256 * 8)), 256, 0, stream>>>(h1pre, scale1, shift1, h1, H1_DIM - 1);
    // 7. GEMM2 (+BN2 stats): h2raw = h1 @ W2
    gemm_stats<float><<<dim3(B_DIM / 64, H2_DIM / 64), 256, 0, stream>>>(
        h1, W2T, h2raw, ps, pq, H2_DIM, H1_DIM);
    // 8. finalize BN2
    col_finalize<<<dim3((H2_DIM + 255) / 256), 256, 0, stream>>>(ps, pq, gamma2, beta2, scale2, shift2,
                                                                 H2_DIM, B_DIM / 64, 1.f / B_DIM);
    // 9. BN2 + lrelu + dot(Wo) + bo -> out [B]
    bn_dot_out<<<dim3(B_DIM), 256, 0, stream>>>(h2raw, scale2, shift2, Wo, bo, out);
}

// Round 5
// 113.467 us; speedup vs baseline: 2.3594x; 1.1845x over previous
//
#include <hip/hip_runtime.h>
#include <hip/hip_bf16.h>

#define B_DIM   1024
#define N_DIM   2048
#define G_DIM   32
#define H1_DIM  2048
#define H2_DIM  512
#define BN_EPS  1e-5f
#define SLOPE   0.05f

typedef short v8s __attribute__((ext_vector_type(8)));
typedef float v4f __attribute__((ext_vector_type(4)));

__device__ __forceinline__ float lrelu_f(float v) { return v >= 0.f ? v : SLOPE * v; }
__device__ __forceinline__ float bf2f(unsigned short u) {
    union { unsigned int i; float f; } c; c.i = ((unsigned int)u) << 16; return c.f;
}
__device__ __forceinline__ unsigned short f2bf(float f) {
    __hip_bfloat16 h = __float2bfloat16(f);
    return *(unsigned short*)&h;
}

// async global->LDS, 16B per lane, linear LDS dest (wave-uniform base + lane*16)
#define GLOAD_LDS16(gp, lp)                                                              \
    __builtin_amdgcn_global_load_lds(                                                    \
        (const __attribute__((address_space(1))) unsigned int*)(gp),                     \
        (__attribute__((address_space(3))) unsigned int*)(lp), 16, 0, 0)

// ---------------------------------------------------------------- fused transpose
// bid < 1024 : W1 [N][H1] -> W1T [H1][N] bf16, rows scaled by softmax(att_w)
//              (softmax computed redundantly per block - deterministic)
// bid >= 1024: W2 [H1][H2] -> W2T [H2][H1] bf16
__global__ __launch_bounds__(256) void fused_transpose(
        const float* __restrict__ W1, const float* __restrict__ W2,
        const float* __restrict__ aw,
        __hip_bfloat16* __restrict__ W1T, __hip_bfloat16* __restrict__ W2T) {
    __shared__ float tile[64][65];
    __shared__ float red[8];
    __shared__ float scl[64];
    int t = threadIdx.x;
    int bid = blockIdx.x;
    const float* W;
    __hip_bfloat16* Wt;
    int Kd, Jd, j0, k0;
    bool doScale;
    if (bid < 1024) {
        W = W1; Wt = W1T; Kd = N_DIM; Jd = H1_DIM;
        j0 = (bid & 31) * 64; k0 = (bid >> 5) * 64; doScale = true;
        // block-redundant softmax over att_w[0..2047]
        float mx = -1e30f;
#pragma unroll
        for (int i = 0; i < 8; ++i) mx = fmaxf(mx, aw[t + i * 256]);
#pragma unroll
        for (int off = 32; off; off >>= 1) mx = fmaxf(mx, __shfl_xor(mx, off, 64));
        if ((t & 63) == 0) red[t >> 6] = mx;
        __syncthreads();
        float M = fmaxf(fmaxf(red[0], red[1]), fmaxf(red[2], red[3]));
        float sm = 0.f;
#pragma unroll
        for (int i = 0; i < 8; ++i) sm += expf(aw[t + i * 256] - M);
#pragma unroll
        for (int off = 32; off; off >>= 1) sm += __shfl_xor(sm, off, 64);
        if ((t & 63) == 0) red[4 + (t >> 6)] = sm;
        __syncthreads();
        float invS = 1.f / (red[4] + red[5] + red[6] + red[7]);
        if (t < 64) scl[t] = expf(aw[k0 + t] - M) * invS;
        __syncthreads();
    } else {
        int b2 = bid - 1024;
        W = W2; Wt = W2T; Kd = H1_DIM; Jd = H2_DIM;
        j0 = (b2 & 7) * 64; k0 = (b2 >> 3) * 64; doScale = false;
    }
#pragma unroll
    for (int p = 0; p < 16; ++p) {
        int r = (t >> 6) + p * 4;
        float v = W[(size_t)(k0 + r) * Jd + j0 + (t & 63)];
        if (doScale) v *= scl[r];
        tile[r][t & 63] = v;
    }
    __syncthreads();
#pragma unroll
    for (int p = 0; p < 8; ++p) {
        int jr = (t >> 5) + p * 8;
        int kc = (t & 31) * 2;
        ushort2 pk;
        pk.x = f2bf(tile[kc][jr]);
        pk.y = f2bf(tile[kc + 1][jr]);
        *(ushort2*)(Wt + (size_t)(j0 + jr) * Kd + k0 + kc) = pk;
    }
}

// ------------------------------------------------ g[b][n] = lrelu(dot(x[b,n*32:], Wg[n]) + bg[n])
// 2 lanes per group (16 elems each): coalesced 64B/lane-pair x reads, 1 shfl.
__global__ __launch_bounds__(256) void group_linear(const float* __restrict__ x,
                                                    const float* __restrict__ Wg,
                                                    const float* __restrict__ bg,
                                                    __hip_bfloat16* __restrict__ g) {
    int t = threadIdx.x;
    int seg = blockIdx.y;                 // 16 segs x 128 groups
    int brow = blockIdx.x;                // 128 brows x 8 batch rows
    int gl = t >> 1, half = t & 1;
    int n = seg * 128 + gl;
    float4 wv[4];
    const float4* wsrc = (const float4*)(Wg + (size_t)n * 32 + half * 16);
#pragma unroll
    for (int q = 0; q < 4; ++q) wv[q] = wsrc[q];
    float bgv = bg[n];
#pragma unroll
    for (int bb = 0; bb < 8; ++bb) {
        int b = brow * 8 + bb;
        const float4* xr = (const float4*)(x + (size_t)b * (N_DIM * G_DIM) + (size_t)n * 32 + half * 16);
        float s = 0.f;
#pragma unroll
        for (int q = 0; q < 4; ++q) {
            float4 v = xr[q];
            s += v.x * wv[q].x + v.y * wv[q].y + v.z * wv[q].z + v.w * wv[q].w;
        }
        s += __shfl_xor(s, 1, 64);
        if (half == 0)
            g[(size_t)b * N_DIM + n] = __float2bfloat16(lrelu_f(s + bgv));
    }
}

// ------------------------------------------------ C[M][N] = A[M][K]bf16 @ Bt[N][K]bf16^T
// 64 x BN_T tile, BK=128, 2-phase double-buffered global_load_lds staging.
// XOR-swizzle: chunk^(row&15); 16 chunks/row -> 2 lanes/bank-group on ds_read (free).
// setprio(1) around MFMA quads. XCD-chunk bijective block swizzle.
// Fused epilogue: per-block-row column sum / sumsq -> ps/pq[bx][N].
template<int BN_T, int TT, typename OutT>
__global__ __launch_bounds__(TT) void gemm_stats(
        const __hip_bfloat16* __restrict__ A, const __hip_bfloat16* __restrict__ Bt,
        OutT* __restrict__ C, float* __restrict__ ps, float* __restrict__ pq,
        int N, int K) {
    constexpr int WC = BN_T / 32;           // wave cols
    constexpr int WR = TT / 64 / WC;        // wave rows (=2)
    __shared__ __hip_bfloat16 A_s[2][64 * 128];
    __shared__ __hip_bfloat16 B_s[2][BN_T * 128];
    __shared__ float rs[WR][BN_T], rq[WR][BN_T];

    // XCD-aware bijective block swizzle (grid multiple of 8)
    int nwg = gridDim.x * gridDim.y;
    int bid = blockIdx.y * gridDim.x + blockIdx.x;
    int cpx = nwg >> 3;
    int wg  = (bid & 7) * cpx + (bid >> 3);
    int bx  = wg % gridDim.x, by = wg / gridDim.x;

    int tid = threadIdx.x, lane = tid & 63, wave = tid >> 6;
    int wr = wave / WC, wc = wave % WC;
    int rbase = bx * 64, cbase = by * BN_T;
    int l15 = lane & 15, kq = lane >> 4;

    v4f acc[2][2] = {};

    auto stage = [&](int buf, int kt) {
        int k0 = kt << 7;
#pragma unroll
        for (int i = 0; i < 1024 / TT; ++i) {
            int s = tid + i * TT;
            int row = s >> 4, cg = (s & 15) ^ (row & 15);
            GLOAD_LDS16(A + (size_t)(rbase + row) * K + k0 + cg * 8, (char*)A_s[buf] + s * 16);
        }
#pragma unroll
        for (int i = 0; i < BN_T * 16 / TT; ++i) {
            int s = tid + i * TT;
            int row = s >> 4, cg = (s & 15) ^ (row & 15);
            GLOAD_LDS16(Bt + (size_t)(cbase + row) * K + k0 + cg * 8, (char*)B_s[buf] + s * 16);
        }
    };

    const int nkt = K >> 7;
    stage(0, 0);
    __syncthreads();
    int cur = 0;
    for (int kt = 0; kt < nkt; ++kt) {
        if (kt + 1 < nkt) stage(cur ^ 1, kt + 1);
#pragma unroll
        for (int kc = 0; kc < 4; ++kc) {
            v8s af[2], bfv[2];
#pragma unroll
            for (int m = 0; m < 2; ++m) {
                int row = wr * 32 + m * 16 + l15;
                int off = row * 256 + (((kc * 4 + kq) ^ (row & 15)) << 4);
                af[m] = *(const v8s*)((const char*)A_s[cur] + off);
            }
#pragma unroll
            for (int n = 0; n < 2; ++n) {
                int row = wc * 32 + n * 16 + l15;
                int off = row * 256 + (((kc * 4 + kq) ^ (row & 15)) << 4);
                bfv[n] = *(const v8s*)((const char*)B_s[cur] + off);
            }
            __builtin_amdgcn_s_setprio(1);
#pragma unroll
            for (int m = 0; m < 2; ++m)
#pragma unroll
                for (int n = 0; n < 2; ++n)
                    acc[m][n] = __builtin_amdgcn_mfma_f32_16x16x32_bf16(af[m], bfv[n],
                                                                        acc[m][n], 0, 0, 0);
            __builtin_amdgcn_s_setprio(0);
        }
        __syncthreads();
        cur ^= 1;
    }

    // ---- C write
    int crow = kq * 4;
#pragma unroll
    for (int m = 0; m < 2; ++m)
#pragma unroll
        for (int n = 0; n < 2; ++n) {
            int r = rbase + wr * 32 + m * 16 + crow;
            int c = cbase + wc * 32 + n * 16 + l15;
#pragma unroll
            for (int i = 0; i < 4; ++i) {
                float v = acc[m][n][i];
                if constexpr (sizeof(OutT) == 2)
                    ((__hip_bfloat16*)C)[(size_t)(r + i) * N + c] = __float2bfloat16(v);
                else
                    ((float*)C)[(size_t)(r + i) * N + c] = v;
            }
        }

    // ---- fused column stats (sum / sumsq over this block's 64 rows)
    float cs[2], cq[2];
#pragma unroll
    for (int n = 0; n < 2; ++n) {
        cs[n] = 0.f; cq[n] = 0.f;
#pragma unroll
        for (int m = 0; m < 2; ++m)
#pragma unroll
            for (int i = 0; i < 4; ++i) {
                float v = acc[m][n][i];
                cs[n] += v; cq[n] += v * v;
            }
#pragma unroll
        for (int off = 16; off <= 32; off <<= 1) {
            cs[n] += __shfl_xor(cs[n], off, 64);
            cq[n] += __shfl_xor(cq[n], off, 64);
        }
    }
    if (lane < 16) {
#pragma unroll
        for (int n = 0; n < 2; ++n) {
            rs[wr][wc * 32 + n * 16 + lane] = cs[n];
            rq[wr][wc * 32 + n * 16 + lane] = cq[n];
        }
    }
    __syncthreads();
    if (tid < BN_T) {
        float s = 0.f, q = 0.f;
#pragma unroll
        for (int w = 0; w < WR; ++w) { s += rs[w][tid]; q += rq[w][tid]; }
        ps[(size_t)bx * N + cbase + tid] = s;
        pq[(size_t)bx * N + cbase + tid] = q;
    }
}

// ------------------------------------------------ BN1 finalize (block-redundant) + apply + lrelu
// grid 128 blocks x 8 rows.  hpre bf16 -> h1 bf16.
__global__ __launch_bounds__(256) void bn_apply_fused(
        const __hip_bfloat16* __restrict__ hpre,
        const float* __restrict__ ps, const float* __restrict__ pq,
        const float* __restrict__ gamma, const float* __restrict__ beta,
        __hip_bfloat16* __restrict__ o) {
    __shared__ float scl[H1_DIM], shf[H1_DIM];
    int t = threadIdx.x;
#pragma unroll
    for (int p = 0; p < 8; ++p) {
        int c = t + p * 256;
        float s = 0.f, q = 0.f;
#pragma unroll
        for (int i = 0; i < 16; ++i) {
            s += ps[i * H1_DIM + c];
            q += pq[i * H1_DIM + c];
        }
        float mu = s * (1.f / B_DIM);
        float var = fmaxf(q * (1.f / B_DIM) - mu * mu, 0.f);
        float rsv = rsqrtf(var + BN_EPS);
        float sc = rsv * gamma[c];
        scl[c] = sc;
        shf[c] = beta[c] - mu * sc;
    }
    __syncthreads();
    int j = t * 8;
    float4 sc0 = *(const float4*)&scl[j];
    float4 sc1 = *(const float4*)&scl[j + 4];
    float4 sh0 = *(const float4*)&shf[j];
    float4 sh1 = *(const float4*)&shf[j + 4];
#pragma unroll
    for (int rr = 0; rr < 8; ++rr) {
        size_t base = (size_t)(blockIdx.x * 8 + rr) * H1_DIM + j;
        v8s v = *(const v8s*)(hpre + base);
        v8s pk;
        pk[0] = (short)f2bf(lrelu_f(bf2f((unsigned short)v[0]) * sc0.x + sh0.x));
        pk[1] = (short)f2bf(lrelu_f(bf2f((unsigned short)v[1]) * sc0.y + sh0.y));
        pk[2] = (short)f2bf(lrelu_f(bf2f((unsigned short)v[2]) * sc0.z + sh0.z));
        pk[3] = (short)f2bf(lrelu_f(bf2f((unsigned short)v[3]) * sc0.w + sh0.w));
        pk[4] = (short)f2bf(lrelu_f(bf2f((unsigned short)v[4]) * sc1.x + sh1.x));
        pk[5] = (short)f2bf(lrelu_f(bf2f((unsigned short)v[5]) * sc1.y + sh1.y));
        pk[6] = (short)f2bf(lrelu_f(bf2f((unsigned short)v[6]) * sc1.z + sh1.z));
        pk[7] = (short)f2bf(lrelu_f(bf2f((unsigned short)v[7]) * sc1.w + sh1.w));
        *(v8s*)(o + base) = pk;
    }
}

// ------------------------------------------------ BN2 finalize (block-redundant) + lrelu + dot(Wo)+bo
// grid 256 blocks x 4 rows.
__global__ __launch_bounds__(256) void bn_dot_fused(
        const float* __restrict__ h2,
        const float* __restrict__ ps, const float* __restrict__ pq,
        const float* __restrict__ gamma, const float* __restrict__ beta,
        const float* __restrict__ Wo, const float* __restrict__ bo,
        float* __restrict__ out) {
    __shared__ float scl[H2_DIM], shf[H2_DIM];
    __shared__ float red[4][4];
    int t = threadIdx.x;
#pragma unroll
    for (int p = 0; p < 2; ++p) {
        int c = t + p * 256;
        float s = 0.f, q = 0.f;
#pragma unroll
        for (int i = 0; i < 16; ++i) {
            s += ps[i * H2_DIM + c];
            q += pq[i * H2_DIM + c];
        }
        float mu = s * (1.f / B_DIM);
        float var = fmaxf(q * (1.f / B_DIM) - mu * mu, 0.f);
        float rsv = rsqrtf(var + BN_EPS);
        float sc = rsv * gamma[c];
        scl[c] = sc;
        shf[c] = beta[c] - mu * sc;
    }
    __syncthreads();
    float accv[4];
#pragma unroll
    for (int r = 0; r < 4; ++r) {
        int b = blockIdx.x * 4 + r;
        float s = 0.f;
#pragma unroll
        for (int p = 0; p < 2; ++p) {
            int jj = t + p * 256;
            float v = lrelu_f(h2[(size_t)b * H2_DIM + jj] * scl[jj] + shf[jj]);
            s += v * Wo[jj];
        }
#pragma unroll
        for (int off = 32; off; off >>= 1) s += __shfl_down(s, off, 64);
        accv[r] = s;
    }
    if ((t & 63) == 0) {
#pragma unroll
        for (int r = 0; r < 4; ++r) red[t >> 6][r] = accv[r];
    }
    __syncthreads();
    if (t < 4)
        out[blockIdx.x * 4 + t] = red[0][t] + red[1][t] + red[2][t] + red[3][t] + bo[0];
}

// ================================================================ host
extern "C" void kernel_launch(void* const* d_in, const int* in_sizes, int n_in,
                              void* d_out, int out_size, void* d_ws, size_t ws_size,
                              hipStream_t stream) {
    const float* x     = (const float*)d_in[0];
    const float* Wg    = (const float*)d_in[1];
    const float* bg    = (const float*)d_in[2];
    const float* att_w = (const float*)d_in[3];
    const float* W1    = (const float*)d_in[4];
    const float* gamma1 = (const float*)d_in[6];
    const float* beta1  = (const float*)d_in[7];
    const float* W2    = (const float*)d_in[8];
    const float* gamma2 = (const float*)d_in[10];
    const float* beta2  = (const float*)d_in[11];
    const float* Wo    = (const float*)d_in[12];
    const float* bo    = (const float*)d_in[13];
    float* out = (float*)d_out;

    char* ws = (char*)d_ws;
    size_t off = 0;
    auto alloc = [&](size_t bytes) {
        void* p = ws + off;
        off = (off + bytes + 255) & ~(size_t)255;
        return p;
    };
    __hip_bfloat16* W1T    = (__hip_bfloat16*)alloc((size_t)H1_DIM * N_DIM * 2);
    __hip_bfloat16* W2T    = (__hip_bfloat16*)alloc((size_t)H2_DIM * H1_DIM * 2);
    __hip_bfloat16* g      = (__hip_bfloat16*)alloc((size_t)B_DIM * N_DIM * 2);
    __hip_bfloat16* h1pre  = (__hip_bfloat16*)alloc((size_t)B_DIM * H1_DIM * 2);
    __hip_bfloat16* h1     = (__hip_bfloat16*)alloc((size_t)B_DIM * H1_DIM * 2);
    float*          h2raw  = (float*)alloc((size_t)B_DIM * H2_DIM * 4);
    float*          ps     = (float*)alloc(16 * H1_DIM * 4);
    float*          pq     = (float*)alloc(16 * H1_DIM * 4);
    (void)ws_size; (void)in_sizes; (void)n_in; (void)out_size;

    // 1. softmax + W1T (scaled) + W2T in one launch
    fused_transpose<<<dim3(1024 + 256), 256, 0, stream>>>(W1, W2, att_w, W1T, W2T);
    // 2. per-group linear + lrelu -> g bf16 [B, N]
    group_linear<<<dim3(B_DIM / 8, N_DIM / 128), 256, 0, stream>>>(x, Wg, bg, g);
    // 3. GEMM1 (+BN1 stats): h1pre = bf16(g @ (att*W1))
    gemm_stats<64, 256, __hip_bfloat16><<<dim3(B_DIM / 64, H1_DIM / 64), 256, 0, stream>>>(
        g, W1T, h1pre, ps, pq, H1_DIM, N_DIM);
    // 4. BN1 finalize + apply + lrelu -> h1 bf16
    bn_apply_fused<<<dim3(B_DIM / 8), 256, 0, stream>>>(h1pre, ps, pq, gamma1, beta1, h1);
    // 5. GEMM2 (+BN2 stats): h2raw = h1 @ W2   (64x32 tiles, 256 blocks)
    gemm_stats<32, 128, float><<<dim3(B_DIM / 64, H2_DIM / 32), 128, 0, stream>>>(
        h1, W2T, h2raw, ps, pq, H2_DIM, H1_DIM);
    // 6. BN2 finalize + lrelu + dot(Wo) + bo -> out [B]
    bn_dot_fused<<<dim3(B_DIM / 4), 256, 0, stream>>>(h2raw, ps, pq, gamma2, beta2, Wo, bo, out);
}